// Round 1
// baseline (463.401 us; speedup 1.0000x reference)
//
#include <hip/hip_runtime.h>
#include <hip/hip_bf16.h>

typedef __attribute__((ext_vector_type(8))) short bf16x8;
typedef __attribute__((ext_vector_type(4))) short bf16x4;
typedef __attribute__((ext_vector_type(4))) float f32x4;
typedef unsigned int u32;
typedef unsigned short ush;

#define SEQ 1024
#define NH 16
#define MTOT 4096   // B*S

__device__ __forceinline__ ush f2bf(float f){
  u32 u = __float_as_uint(f);
  u32 r = (u + 0x7fffu + ((u >> 16) & 1u)) >> 16;
  return (ush)r;
}

__device__ __forceinline__ f32x4 mfma16(bf16x8 a, bf16x8 b, f32x4 c){
  return __builtin_amdgcn_mfma_f32_16x16x32_bf16(a, b, c, 0, 0, 0);
}

__device__ __forceinline__ void gload_lds16(const ush* g, ush* l){
  __builtin_amdgcn_global_load_lds(
      (const __attribute__((address_space(1))) u32*)g,
      (__attribute__((address_space(3))) u32*)l, 16, 0, 0);
}

// ---------------- elementwise convert f32 -> bf16 ----------------
__global__ __launch_bounds__(256) void cvt_kernel(const float* __restrict__ src,
                                                  ush* __restrict__ dst, int n){
  int i = (blockIdx.x * 256 + threadIdx.x) * 4;
  if (i < n){
    float4 v = *(const float4*)&src[i];
    ushort4 o = { f2bf(v.x), f2bf(v.y), f2bf(v.z), f2bf(v.w) };
    *(ushort4*)&dst[i] = o;
  }
}

// ---------------- transpose + convert: dst[c][r] = bf16(src[r][c]) ----------------
__global__ __launch_bounds__(256) void tconv_kernel(const float* __restrict__ src,
                                                    ush* __restrict__ dst, int R, int C){
  __shared__ float t[32][33];
  int tx = threadIdx.x & 31, ty = threadIdx.x >> 5;
  int r0 = blockIdx.y * 32, c0 = blockIdx.x * 32;
  #pragma unroll
  for (int i = 0; i < 32; i += 8)
    t[ty + i][tx] = src[(size_t)(r0 + ty + i) * C + (c0 + tx)];
  __syncthreads();
  #pragma unroll
  for (int i = 0; i < 32; i += 8)
    dst[(size_t)(c0 + ty + i) * R + (r0 + tx)] = f2bf(t[tx][ty + i]);
}

__global__ __launch_bounds__(256) void biaspack_kernel(const float* __restrict__ bq,
    const float* __restrict__ bk, const float* __restrict__ bv, float* __restrict__ dst){
  int i = blockIdx.x * 256 + threadIdx.x;
  if (i < 3072){
    float v = (i < 1024) ? bq[i] : (i < 2048) ? bk[i - 1024] : bv[i - 2048];
    dst[i] = v;
  }
}

// ---------------- GEMM: C[M,N] = A[M,K](bf16) @ Bt[N,K]^T(bf16) + bias ----------------
// m97 structure: 128x128 tile, BK=32, 4 waves (2x2), global_load_lds width 16.
template<bool RELU, bool OUTF32>
__global__ __launch_bounds__(256) void gemm_kernel(
    const ush* __restrict__ A, const ush* __restrict__ Bt,
    const float* __restrict__ bias,
    float* __restrict__ Cf, ush* __restrict__ Cb,
    int M, int N, int K, int ldc)
{
  __shared__ ush As[128 * 32];
  __shared__ ush Bs[128 * 32];
  const int tid = threadIdx.x;
  const int lane = tid & 63, wid = tid >> 6;
  const int g = lane >> 4, qr = lane & 15;
  const int bm = blockIdx.y * 128, bn = blockIdx.x * 128;
  const int srow = lane >> 2, scol = (lane & 3) * 8;
  const ush* aA0 = A  + (size_t)(bm + wid * 16 + srow) * K + scol;
  const ush* aB0 = Bt + (size_t)(bn + wid * 16 + srow) * K + scol;
  const ush* aA1 = aA0 + (size_t)64 * K;
  const ush* aB1 = aB0 + (size_t)64 * K;
  ush* lA0 = As + wid * 512;
  ush* lA1 = As + (4 + wid) * 512;
  ush* lB0 = Bs + wid * 512;
  ush* lB1 = Bs + (4 + wid) * 512;
  const int wm = (wid >> 1) * 64, wn = (wid & 1) * 64;
  f32x4 acc[4][4] = {};
  for (int kt = 0; kt < K; kt += 32){
    __syncthreads();
    gload_lds16(aA0 + kt, lA0);
    gload_lds16(aA1 + kt, lA1);
    gload_lds16(aB0 + kt, lB0);
    gload_lds16(aB1 + kt, lB1);
    __syncthreads();
    bf16x8 af[4], bfr[4];
    #pragma unroll
    for (int i = 0; i < 4; i++){
      af[i]  = *(const bf16x8*)(As + (wm + i * 16 + qr) * 32 + g * 8);
      bfr[i] = *(const bf16x8*)(Bs + (wn + i * 16 + qr) * 32 + g * 8);
    }
    #pragma unroll
    for (int i = 0; i < 4; i++)
      #pragma unroll
      for (int j = 0; j < 4; j++)
        acc[i][j] = mfma16(af[i], bfr[j], acc[i][j]);
  }
  const int row0 = bm + wm + g * 4;
  const int col0 = bn + wn + qr;
  #pragma unroll
  for (int j = 0; j < 4; j++){
    const int col = col0 + j * 16;
    const float bv = bias[col];
    #pragma unroll
    for (int i = 0; i < 4; i++){
      #pragma unroll
      for (int r = 0; r < 4; r++){
        float v = acc[i][j][r] + bv;
        if (RELU) v = fmaxf(v, 0.f);
        const size_t idx = (size_t)(row0 + i * 16 + r) * ldc + col;
        if (OUTF32) Cf[idx] = v; else Cb[idx] = f2bf(v);
      }
    }
  }
}

// ---------------- flash attention ----------------
// qkv: [4096][3072] bf16 (Q|K|V each 1024 cols). ctx out: [4096][1024] bf16.
// Block: 4 waves, 64 q-rows (16/wave). Swapped QK^T: S^T = mfma(K_frag, Q^T_frag).
__global__ __launch_bounds__(256) void attn_kernel(
    const ush* __restrict__ qkv, const int* __restrict__ mask,
    ush* __restrict__ ctx)
{
  __shared__ ush Vt[64 * 40];       // V^T tile: [d][key], stride 40
  __shared__ ush Pl[4][16 * 40];    // per-wave P: [q][key], stride 40
  __shared__ int mk[1024];
  const int tid = threadIdx.x;
  const int lane = tid & 63, w = tid >> 6;
  const int g = lane >> 4, qr = lane & 15;
  const int hb = blockIdx.y;
  const int b = hb >> 4, hh = hb & 15;
  const int qt = blockIdx.x;

  { int4 mv = *(const int4*)&mask[b * SEQ + tid * 4]; *(int4*)&mk[tid * 4] = mv; }
  __syncthreads();

  const size_t rowQ = (size_t)(b * SEQ + qt * 64 + w * 16 + qr);
  const ush* Qp = qkv + rowQ * 3072 + hh * 64;
  bf16x8 qf0 = *(const bf16x8*)(Qp + g * 8);
  bf16x8 qf1 = *(const bf16x8*)(Qp + 32 + g * 8);

  const ush* Kb = qkv + (size_t)b * SEQ * 3072 + 1024 + hh * 64;
  const ush* Vb = qkv + (size_t)b * SEQ * 3072 + 2048 + hh * 64;

  f32x4 oa[4] = {};
  float m_run = -1e30f, l_run = 0.f;
  const int vkey = tid >> 3, vd0 = (tid & 7) * 8;

  for (int kt = 0; kt < SEQ / 32; ++kt){
    const int k0 = kt * 32;
    // prefetch V tile to regs (consumed after barrier)
    bf16x8 vv = *(const bf16x8*)(Vb + (size_t)(k0 + vkey) * 3072 + vd0);
    // K fragments (direct from global; L2-resident) + QK^T
    const ush* Kr0 = Kb + (size_t)(k0 + qr) * 3072;
    const ush* Kr1 = Kr0 + (size_t)16 * 3072;
    bf16x8 ka0 = *(const bf16x8*)(Kr0 + g * 8);
    bf16x8 ka1 = *(const bf16x8*)(Kr0 + 32 + g * 8);
    bf16x8 kb0 = *(const bf16x8*)(Kr1 + g * 8);
    bf16x8 kb1 = *(const bf16x8*)(Kr1 + 32 + g * 8);
    f32x4 z = {0.f, 0.f, 0.f, 0.f};
    f32x4 st0 = mfma16(ka0, qf0, z); st0 = mfma16(ka1, qf1, st0);
    f32x4 st1 = mfma16(kb0, qf0, z); st1 = mfma16(kb1, qf1, st1);
    // scale + mask ; S^T frag: row=key=g*4+r(+16), col=q=qr
    float sc[8];
    #pragma unroll
    for (int r = 0; r < 4; r++){
      int key = k0 + g * 4 + r;
      sc[r]     = (mk[key] == 0)      ? -1e9f : st0[r] * 0.125f;
      sc[4 + r] = (mk[key + 16] == 0) ? -1e9f : st1[r] * 0.125f;
    }
    // online softmax over this 32-key tile (per q = qr column group)
    float pm = sc[0];
    #pragma unroll
    for (int r = 1; r < 8; r++) pm = fmaxf(pm, sc[r]);
    pm = fmaxf(pm, __shfl_xor(pm, 16));
    pm = fmaxf(pm, __shfl_xor(pm, 32));
    float m_new = fmaxf(m_run, pm);
    float corr = __expf(m_run - m_new);
    float ls = 0.f;
    #pragma unroll
    for (int r = 0; r < 8; r++){ sc[r] = __expf(sc[r] - m_new); ls += sc[r]; }
    ls += __shfl_xor(ls, 16); ls += __shfl_xor(ls, 32);
    l_run = l_run * corr + ls; m_run = m_new;
    // rescale O accumulator (O rows are q' = g*4+r; corr lives at lane q')
    #pragma unroll
    for (int r = 0; r < 4; r++){
      float cr = __shfl(corr, g * 4 + r);
      oa[0][r] *= cr; oa[1][r] *= cr; oa[2][r] *= cr; oa[3][r] *= cr;
    }
    // P -> LDS (wave-private): [q][key] with 4 consecutive keys per write
    bf16x4 p0, p1;
    #pragma unroll
    for (int r = 0; r < 4; r++){ p0[r] = (short)f2bf(sc[r]); p1[r] = (short)f2bf(sc[4 + r]); }
    *(bf16x4*)&Pl[w][qr * 40 + g * 4]      = p0;
    *(bf16x4*)&Pl[w][qr * 40 + 16 + g * 4] = p1;
    // V^T stage (block-coop)
    __syncthreads();
    #pragma unroll
    for (int j = 0; j < 8; j++) Vt[(vd0 + j) * 40 + vkey] = (ush)vv[j];
    __syncthreads();
    // PV: O += P @ V
    bf16x8 pf = *(const bf16x8*)&Pl[w][qr * 40 + g * 8];
    #pragma unroll
    for (int d = 0; d < 4; d++){
      bf16x8 vf = *(const bf16x8*)&Vt[(d * 16 + qr) * 40 + g * 8];
      oa[d] = mfma16(pf, vf, oa[d]);
    }
  }
  float linv = 1.f / l_run;
  #pragma unroll
  for (int r = 0; r < 4; r++){
    float lr = __shfl(linv, g * 4 + r);
    size_t rowO = (size_t)(b * SEQ + qt * 64 + w * 16 + g * 4 + r);
    #pragma unroll
    for (int d = 0; d < 4; d++)
      ctx[rowO * 1024 + hh * 64 + d * 16 + qr] = f2bf(oa[d][r] * lr);
  }
}

// ---------------- residual + LayerNorm ----------------
template<bool WB>
__global__ __launch_bounds__(256) void ln_kernel(
    const float* __restrict__ X, const float* __restrict__ Y,
    const float* __restrict__ gam, const float* __restrict__ bet,
    float* __restrict__ Of, ush* __restrict__ Ob)
{
  const int row = blockIdx.x, tid = threadIdx.x;
  const size_t base = (size_t)row * 1024 + tid * 4;
  float4 xv = *(const float4*)&X[base];
  float4 yv = *(const float4*)&Y[base];
  float s0 = xv.x + yv.x, s1 = xv.y + yv.y, s2 = xv.z + yv.z, s3 = xv.w + yv.w;
  float sum = s0 + s1 + s2 + s3;
  float sq  = s0 * s0 + s1 * s1 + s2 * s2 + s3 * s3;
  #pragma unroll
  for (int o = 1; o < 64; o <<= 1){ sum += __shfl_xor(sum, o); sq += __shfl_xor(sq, o); }
  __shared__ float red[8];
  int lane = tid & 63, w = tid >> 6;
  if (lane == 0){ red[w] = sum; red[4 + w] = sq; }
  __syncthreads();
  sum = red[0] + red[1] + red[2] + red[3];
  sq  = red[4] + red[5] + red[6] + red[7];
  float mean = sum * (1.f / 1024.f);
  float var  = sq * (1.f / 1024.f) - mean * mean;
  float rs = rsqrtf(var + 1e-5f);
  float4 gv = *(const float4*)&gam[tid * 4];
  float4 bv = *(const float4*)&bet[tid * 4];
  float o0 = (s0 - mean) * rs * gv.x + bv.x;
  float o1 = (s1 - mean) * rs * gv.y + bv.y;
  float o2 = (s2 - mean) * rs * gv.z + bv.z;
  float o3 = (s3 - mean) * rs * gv.w + bv.w;
  float4 ov = { o0, o1, o2, o3 };
  *(float4*)&Of[base] = ov;
  if (WB){
    ushort4 ob = { f2bf(o0), f2bf(o1), f2bf(o2), f2bf(o3) };
    *(ushort4*)&Ob[base] = ob;
  }
}

// ---------------- orchestration ----------------
extern "C" void kernel_launch(void* const* d_in, const int* in_sizes, int n_in,
                              void* d_out, int out_size, void* d_ws, size_t ws_size,
                              hipStream_t stream)
{
  const float* x    = (const float*)d_in[0];
  const int*   mask = (const int*)  d_in[1];
  const float* Wq = (const float*)d_in[2];
  const float* bq = (const float*)d_in[3];
  const float* Wk = (const float*)d_in[4];
  const float* bk = (const float*)d_in[5];
  const float* Wv = (const float*)d_in[6];
  const float* bv = (const float*)d_in[7];
  const float* Wo = (const float*)d_in[8];
  const float* bo = (const float*)d_in[9];
  const float* W1 = (const float*)d_in[10];
  const float* b1 = (const float*)d_in[11];
  const float* W2 = (const float*)d_in[12];
  const float* b2 = (const float*)d_in[13];
  const float* g1 = (const float*)d_in[14];
  const float* be1= (const float*)d_in[15];
  const float* g2 = (const float*)d_in[16];
  const float* be2= (const float*)d_in[17];
  float* out = (float*)d_out;

  char* ws = (char*)d_ws;
  size_t off = 0;
  auto alloc = [&](size_t bytes)->void*{ void* p = ws + off; off += (bytes + 255) & ~(size_t)255; return p; };
  ush* xb     = (ush*)alloc((size_t)MTOT * 1024 * 2);
  ush* wqkvT  = (ush*)alloc((size_t)3072 * 1024 * 2);
  ush* woT    = (ush*)alloc((size_t)1024 * 1024 * 2);
  ush* w1T    = (ush*)alloc((size_t)4096 * 1024 * 2);
  ush* w2T    = (ush*)alloc((size_t)1024 * 4096 * 2);
  float* bqkv = (float*)alloc(3072 * 4);
  ush* qkv    = (ush*)alloc((size_t)MTOT * 3072 * 2);   // + ctx region reused as ff1
  ush* ctx    = (ush*)alloc((size_t)MTOT * 1024 * 2);
  float* attn_out = (float*)alloc((size_t)MTOT * 1024 * 4);  // reused as ff2
  float* h    = (float*)alloc((size_t)MTOT * 1024 * 4);
  ush* hb     = (ush*)alloc((size_t)MTOT * 1024 * 2);
  ush* ff1    = qkv;        // 32 MB span (qkv 24MB + ctx 8MB), both dead by then
  float* ff2  = attn_out;   // attn_out dead after LN1

  // 1. converts / transposes
  cvt_kernel<<<dim3(4096), dim3(256), 0, stream>>>(x, xb, MTOT * 1024);
  tconv_kernel<<<dim3(32, 32), dim3(256), 0, stream>>>(Wq, wqkvT,                 1024, 1024);
  tconv_kernel<<<dim3(32, 32), dim3(256), 0, stream>>>(Wk, wqkvT + 1024 * 1024,   1024, 1024);
  tconv_kernel<<<dim3(32, 32), dim3(256), 0, stream>>>(Wv, wqkvT + 2048 * 1024,   1024, 1024);
  tconv_kernel<<<dim3(32, 32), dim3(256), 0, stream>>>(Wo, woT,                   1024, 1024);
  tconv_kernel<<<dim3(128, 32), dim3(256), 0, stream>>>(W1, w1T, 1024, 4096);
  tconv_kernel<<<dim3(32, 128), dim3(256), 0, stream>>>(W2, w2T, 4096, 1024);
  biaspack_kernel<<<dim3(12), dim3(256), 0, stream>>>(bq, bk, bv, bqkv);

  // 2. QKV projection: [4096,3072]
  gemm_kernel<false, false><<<dim3(24, 32), dim3(256), 0, stream>>>(
      xb, wqkvT, bqkv, nullptr, qkv, MTOT, 3072, 1024, 3072);

  // 3. attention -> ctx bf16 [4096,1024]
  attn_kernel<<<dim3(16, 64), dim3(256), 0, stream>>>(qkv, mask, ctx);

  // 4. attn_out = ctx @ Wo + bo (f32)
  gemm_kernel<false, true><<<dim3(8, 32), dim3(256), 0, stream>>>(
      ctx, woT, bo, attn_out, nullptr, MTOT, 1024, 1024, 1024);

  // 5. h = LN(x + attn_out)  (f32 + bf16)
  ln_kernel<true><<<dim3(4096), dim3(256), 0, stream>>>(x, attn_out, g1, be1, h, hb);

  // 6. ff1 = relu(h @ W1 + b1) (bf16 [4096,4096])
  gemm_kernel<true, false><<<dim3(32, 32), dim3(256), 0, stream>>>(
      hb, w1T, b1, nullptr, ff1, MTOT, 4096, 1024, 4096);

  // 7. ff2 = ff1 @ W2 + b2 (f32)
  gemm_kernel<false, true><<<dim3(8, 32), dim3(256), 0, stream>>>(
      ff1, w2T, b2, ff2, nullptr, MTOT, 1024, 4096, 1024);

  // 8. out = LN(h + ff2)
  ln_kernel<false><<<dim3(4096), dim3(256), 0, stream>>>(h, ff2, g2, be2, out, nullptr);
}

// Round 2
// 416.588 us; speedup vs baseline: 1.1124x; 1.1124x over previous
//
#include <hip/hip_runtime.h>
#include <hip/hip_bf16.h>

typedef __attribute__((ext_vector_type(8))) short bf16x8;
typedef __attribute__((ext_vector_type(4))) short bf16x4;
typedef __attribute__((ext_vector_type(4))) float f32x4;
typedef unsigned int u32;
typedef unsigned short ush;

#define SEQ 1024
#define MTOT 4096   // B*S

__device__ __forceinline__ ush f2bf(float f){
  u32 u = __float_as_uint(f);
  u32 r = (u + 0x7fffu + ((u >> 16) & 1u)) >> 16;
  return (ush)r;
}

__device__ __forceinline__ f32x4 mfma16(bf16x8 a, bf16x8 b, f32x4 c){
  return __builtin_amdgcn_mfma_f32_16x16x32_bf16(a, b, c, 0, 0, 0);
}

__device__ __forceinline__ void gload_lds16(const ush* g, ush* l){
  __builtin_amdgcn_global_load_lds(
      (const __attribute__((address_space(1))) u32*)g,
      (__attribute__((address_space(3))) u32*)l, 16, 0, 0);
}

// ---------------- elementwise convert f32 -> bf16 ----------------
__global__ __launch_bounds__(256) void cvt_kernel(const float* __restrict__ src,
                                                  ush* __restrict__ dst, int n){
  int i = (blockIdx.x * 256 + threadIdx.x) * 4;
  if (i < n){
    float4 v = *(const float4*)&src[i];
    ushort4 o = { f2bf(v.x), f2bf(v.y), f2bf(v.z), f2bf(v.w) };
    *(ushort4*)&dst[i] = o;
  }
}

// ---------------- transpose + convert: dst[c][r] = bf16(src[r][c]) ----------------
__global__ __launch_bounds__(256) void tconv_kernel(const float* __restrict__ src,
                                                    ush* __restrict__ dst, int R, int C){
  __shared__ float t[32][33];
  int tx = threadIdx.x & 31, ty = threadIdx.x >> 5;
  int r0 = blockIdx.y * 32, c0 = blockIdx.x * 32;
  #pragma unroll
  for (int i = 0; i < 32; i += 8)
    t[ty + i][tx] = src[(size_t)(r0 + ty + i) * C + (c0 + tx)];
  __syncthreads();
  #pragma unroll
  for (int i = 0; i < 32; i += 8)
    dst[(size_t)(c0 + ty + i) * R + (r0 + tx)] = f2bf(t[tx][ty + i]);
}

__global__ __launch_bounds__(256) void biaspack_kernel(const float* __restrict__ bq,
    const float* __restrict__ bk, const float* __restrict__ bv, float* __restrict__ dst){
  int i = blockIdx.x * 256 + threadIdx.x;
  if (i < 3072){
    float v = (i < 1024) ? bq[i] : (i < 2048) ? bk[i - 1024] : bv[i - 2048];
    dst[i] = v;
  }
}

// =====================================================================
// 256x256 8-phase GEMM (plain-HIP port of the m201 template, K-half pieces)
// C[M,N] = A[M,K] @ Bt[N,K]^T (+bias/relu).  8 waves (2M x 4N), BK=64.
// LDS: [buf][mat][ks][256 rows][32 cols] pieces of 16KB, 128KB total.
// Swizzle: 16B chunk-in-row ^= (row>>1)&3 (involution); staged pre-swizzled
// via per-lane global source (global_load_lds dest is linear).
// =====================================================================
__device__ __forceinline__ void stage_piece(ush* piece, const ush* g0, int K,
                                            int tid, int w){
  #pragma unroll
  for (int I = 0; I < 2; I++){
    int c = I * 512 + tid;
    int r = c >> 2;
    int gl = (c & 3) ^ ((r >> 1) & 3);
    gload_lds16(g0 + (size_t)r * K + gl * 8, piece + I * 4096 + w * 512);
  }
}

__device__ __forceinline__ bf16x8 frag(const ush* piece, int row, int g){
  int phys = g ^ ((row >> 1) & 3);
  return *(const bf16x8*)(piece + row * 32 + phys * 8);
}

#define PH_BAR_TOP() do{ __builtin_amdgcn_sched_barrier(0); \
  __builtin_amdgcn_s_barrier(); \
  asm volatile("s_waitcnt lgkmcnt(0)" ::: "memory"); \
  __builtin_amdgcn_sched_barrier(0); \
  __builtin_amdgcn_s_setprio(1); }while(0)
#define PH_BAR_BOT() do{ __builtin_amdgcn_s_setprio(0); \
  __builtin_amdgcn_sched_barrier(0); \
  __builtin_amdgcn_s_barrier(); }while(0)

template<int RELU, int OUTF32>
__global__ __launch_bounds__(512, 2) void gemm8_kernel(
    const ush* __restrict__ A, const ush* __restrict__ Bt,
    const float* __restrict__ bias,
    ush* __restrict__ Cb, float* __restrict__ Cf,
    int M, int N, int K, int ldc, int ksl)
{
  __shared__ ush lds[2][2][2][8192];   // [buf][A/B][ks][16KB piece]
  const int tid = threadIdx.x;
  const int lane = tid & 63, w = tid >> 6;
  const int g = lane >> 4, qr = lane & 15;
  const int wr = w >> 2, wc = w & 3;
  // XCD-aware bijective swizzle (all grids have nwg % 8 == 0)
  const int gx = gridDim.x;
  const int nwg = gx * gridDim.y;
  const int id = blockIdx.y * gx + blockIdx.x;
  const int swz = (id & 7) * (nwg >> 3) + (id >> 3);
  const int bn = (swz % gx) * 256;
  const int bm = (swz / gx) * 256;
  const int kbase = blockIdx.z * ksl;
  const int NT = ksl >> 6;
  const ush* Ab = A  + (size_t)bm * K + kbase;
  const ush* Bb = Bt + (size_t)bn * K + kbase;

  // prologue: tile0 (4 pieces) + tile1 h0 (2 pieces); leave last 2 in flight
  stage_piece(lds[0][0][0], Ab,      K, tid, w);
  stage_piece(lds[0][1][0], Bb,      K, tid, w);
  stage_piece(lds[0][0][1], Ab + 32, K, tid, w);
  stage_piece(lds[0][1][1], Bb + 32, K, tid, w);
  if (NT > 1){
    stage_piece(lds[1][0][0], Ab + 64, K, tid, w);
    stage_piece(lds[1][1][0], Bb + 64, K, tid, w);
  }
  asm volatile("s_waitcnt vmcnt(4)" ::: "memory");
  __builtin_amdgcn_sched_barrier(0);
  __builtin_amdgcn_s_barrier();

  f32x4 acc[8][4] = {};
  const int ar = wr * 128 + qr;
  const int br = wc * 64 + qr;

  for (int T = 0; T < NT; ++T){
    const int cb = T & 1, nb = cb ^ 1;
    const ush* An = Ab + (size_t)(T + 1) * 64;
    const ush* Bn = Bb + (size_t)(T + 1) * 64;
    const ush* Af = Ab + (size_t)(T + 2) * 64;
    const ush* Bf = Bb + (size_t)(T + 2) * 64;
    bf16x8 af[4], bfr[4];

    // ---- phase 1: ks0, m-frags 0-3 (loads all B ks0) ----
    #pragma unroll
    for (int j = 0; j < 4; j++) bfr[j] = frag(lds[cb][1][0], br + j * 16, g);
    #pragma unroll
    for (int i = 0; i < 4; i++) af[i] = frag(lds[cb][0][0], ar + i * 16, g);
    if (T + 1 < NT) stage_piece(lds[nb][0][1], An + 32, K, tid, w);
    PH_BAR_TOP();
    #pragma unroll
    for (int i = 0; i < 4; i++)
      #pragma unroll
      for (int j = 0; j < 4; j++)
        acc[i][j] = mfma16(af[i], bfr[j], acc[i][j]);
    PH_BAR_BOT();

    // ---- phase 2: ks0, m-frags 4-7 (B reused in regs) ----
    #pragma unroll
    for (int i = 0; i < 4; i++) af[i] = frag(lds[cb][0][0], ar + 64 + i * 16, g);
    if (T + 1 < NT) stage_piece(lds[nb][1][1], Bn + 32, K, tid, w);
    PH_BAR_TOP();
    #pragma unroll
    for (int i = 0; i < 4; i++)
      #pragma unroll
      for (int j = 0; j < 4; j++)
        acc[4 + i][j] = mfma16(af[i], bfr[j], acc[4 + i][j]);
    PH_BAR_BOT();

    // ---- phase 3: ks1, m-frags 0-3 (loads all B ks1) ----
    #pragma unroll
    for (int j = 0; j < 4; j++) bfr[j] = frag(lds[cb][1][1], br + j * 16, g);
    #pragma unroll
    for (int i = 0; i < 4; i++) af[i] = frag(lds[cb][0][1], ar + i * 16, g);
    if (T + 2 < NT) stage_piece(lds[cb][0][0], Af, K, tid, w);
    PH_BAR_TOP();
    #pragma unroll
    for (int i = 0; i < 4; i++)
      #pragma unroll
      for (int j = 0; j < 4; j++)
        acc[i][j] = mfma16(af[i], bfr[j], acc[i][j]);
    PH_BAR_BOT();

    // ---- phase 4: ks1, m-frags 4-7 ----
    #pragma unroll
    for (int i = 0; i < 4; i++) af[i] = frag(lds[cb][0][1], ar + 64 + i * 16, g);
    if (T + 2 < NT) stage_piece(lds[cb][1][0], Bf, K, tid, w);
    PH_BAR_TOP();
    #pragma unroll
    for (int i = 0; i < 4; i++)
      #pragma unroll
      for (int j = 0; j < 4; j++)
        acc[4 + i][j] = mfma16(af[i], bfr[j], acc[4 + i][j]);
    __builtin_amdgcn_s_setprio(0);
    __builtin_amdgcn_sched_barrier(0);
    asm volatile("s_waitcnt vmcnt(4)" ::: "memory");   // T+1 fully staged
    __builtin_amdgcn_sched_barrier(0);
    __builtin_amdgcn_s_barrier();
  }

  // ---- epilogue ----
  float* Cfz = Cf;
  if (OUTF32) Cfz = Cf + (size_t)blockIdx.z * M * ldc;
  #pragma unroll
  for (int j = 0; j < 4; j++){
    const int col = bn + wc * 64 + j * 16 + qr;
    const float bv = OUTF32 ? 0.f : bias[col];
    #pragma unroll
    for (int i = 0; i < 8; i++){
      const int row0 = bm + wr * 128 + i * 16 + g * 4;
      #pragma unroll
      for (int rr = 0; rr < 4; rr++){
        float v = acc[i][j][rr] + bv;
        if (RELU) v = fmaxf(v, 0.f);
        const size_t idx = (size_t)(row0 + rr) * ldc + col;
        if (OUTF32) Cfz[idx] = v; else Cb[idx] = f2bf(v);
      }
    }
  }
}

// ---------------- flash attention (unchanged this round) ----------------
__global__ __launch_bounds__(256) void attn_kernel(
    const ush* __restrict__ qkv, const int* __restrict__ mask,
    ush* __restrict__ ctx)
{
  __shared__ ush Vt[64 * 40];
  __shared__ ush Pl[4][16 * 40];
  __shared__ int mk[1024];
  const int tid = threadIdx.x;
  const int lane = tid & 63, w = tid >> 6;
  const int g = lane >> 4, qr = lane & 15;
  const int hb = blockIdx.y;
  const int b = hb >> 4, hh = hb & 15;
  const int qt = blockIdx.x;

  { int4 mv = *(const int4*)&mask[b * SEQ + tid * 4]; *(int4*)&mk[tid * 4] = mv; }
  __syncthreads();

  const size_t rowQ = (size_t)(b * SEQ + qt * 64 + w * 16 + qr);
  const ush* Qp = qkv + rowQ * 3072 + hh * 64;
  bf16x8 qf0 = *(const bf16x8*)(Qp + g * 8);
  bf16x8 qf1 = *(const bf16x8*)(Qp + 32 + g * 8);

  const ush* Kb = qkv + (size_t)b * SEQ * 3072 + 1024 + hh * 64;
  const ush* Vb = qkv + (size_t)b * SEQ * 3072 + 2048 + hh * 64;

  f32x4 oa[4] = {};
  float m_run = -1e30f, l_run = 0.f;
  const int vkey = tid >> 3, vd0 = (tid & 7) * 8;

  for (int kt = 0; kt < SEQ / 32; ++kt){
    const int k0 = kt * 32;
    bf16x8 vv = *(const bf16x8*)(Vb + (size_t)(k0 + vkey) * 3072 + vd0);
    const ush* Kr0 = Kb + (size_t)(k0 + qr) * 3072;
    const ush* Kr1 = Kr0 + (size_t)16 * 3072;
    bf16x8 ka0 = *(const bf16x8*)(Kr0 + g * 8);
    bf16x8 ka1 = *(const bf16x8*)(Kr0 + 32 + g * 8);
    bf16x8 kb0 = *(const bf16x8*)(Kr1 + g * 8);
    bf16x8 kb1 = *(const bf16x8*)(Kr1 + 32 + g * 8);
    f32x4 z = {0.f, 0.f, 0.f, 0.f};
    f32x4 st0 = mfma16(ka0, qf0, z); st0 = mfma16(ka1, qf1, st0);
    f32x4 st1 = mfma16(kb0, qf0, z); st1 = mfma16(kb1, qf1, st1);
    float sc[8];
    #pragma unroll
    for (int r = 0; r < 4; r++){
      int key = k0 + g * 4 + r;
      sc[r]     = (mk[key] == 0)      ? -1e9f : st0[r] * 0.125f;
      sc[4 + r] = (mk[key + 16] == 0) ? -1e9f : st1[r] * 0.125f;
    }
    float pm = sc[0];
    #pragma unroll
    for (int r = 1; r < 8; r++) pm = fmaxf(pm, sc[r]);
    pm = fmaxf(pm, __shfl_xor(pm, 16));
    pm = fmaxf(pm, __shfl_xor(pm, 32));
    float m_new = fmaxf(m_run, pm);
    float corr = __expf(m_run - m_new);
    float ls = 0.f;
    #pragma unroll
    for (int r = 0; r < 8; r++){ sc[r] = __expf(sc[r] - m_new); ls += sc[r]; }
    ls += __shfl_xor(ls, 16); ls += __shfl_xor(ls, 32);
    l_run = l_run * corr + ls; m_run = m_new;
    #pragma unroll
    for (int r = 0; r < 4; r++){
      float cr = __shfl(corr, g * 4 + r);
      oa[0][r] *= cr; oa[1][r] *= cr; oa[2][r] *= cr; oa[3][r] *= cr;
    }
    bf16x4 p0, p1;
    #pragma unroll
    for (int r = 0; r < 4; r++){ p0[r] = (short)f2bf(sc[r]); p1[r] = (short)f2bf(sc[4 + r]); }
    *(bf16x4*)&Pl[w][qr * 40 + g * 4]      = p0;
    *(bf16x4*)&Pl[w][qr * 40 + 16 + g * 4] = p1;
    __syncthreads();
    #pragma unroll
    for (int j = 0; j < 8; j++) Vt[(vd0 + j) * 40 + vkey] = (ush)vv[j];
    __syncthreads();
    bf16x8 pf = *(const bf16x8*)&Pl[w][qr * 40 + g * 8];
    #pragma unroll
    for (int d = 0; d < 4; d++){
      bf16x8 vf = *(const bf16x8*)&Vt[(d * 16 + qr) * 40 + g * 8];
      oa[d] = mfma16(pf, vf, oa[d]);
    }
  }
  float linv = 1.f / l_run;
  #pragma unroll
  for (int r = 0; r < 4; r++){
    float lr = __shfl(linv, g * 4 + r);
    size_t rowO = (size_t)(b * SEQ + qt * 64 + w * 16 + g * 4 + r);
    #pragma unroll
    for (int d = 0; d < 4; d++)
      ctx[rowO * 1024 + hh * 64 + d * 16 + qr] = f2bf(oa[d][r] * lr);
  }
}

// -------- residual + 4-way split-K reduce + bias + LayerNorm --------
template<bool WB>
__global__ __launch_bounds__(256) void ln4_kernel(
    const float* __restrict__ X, const float* __restrict__ P,
    const float* __restrict__ bias,
    const float* __restrict__ gam, const float* __restrict__ bet,
    float* __restrict__ Of, ush* __restrict__ Ob)
{
  const int row = blockIdx.x, tid = threadIdx.x;
  const size_t base = (size_t)row * 1024 + tid * 4;
  float4 xv = *(const float4*)&X[base];
  float4 bv4 = *(const float4*)&bias[tid * 4];
  float s0 = xv.x + bv4.x, s1 = xv.y + bv4.y, s2 = xv.z + bv4.z, s3 = xv.w + bv4.w;
  #pragma unroll
  for (int z = 0; z < 4; z++){
    float4 p = *(const float4*)&P[(size_t)z * 4194304 + base];
    s0 += p.x; s1 += p.y; s2 += p.z; s3 += p.w;
  }
  float sum = s0 + s1 + s2 + s3;
  float sq  = s0 * s0 + s1 * s1 + s2 * s2 + s3 * s3;
  #pragma unroll
  for (int o = 1; o < 64; o <<= 1){ sum += __shfl_xor(sum, o); sq += __shfl_xor(sq, o); }
  __shared__ float red[8];
  int lane = tid & 63, w = tid >> 6;
  if (lane == 0){ red[w] = sum; red[4 + w] = sq; }
  __syncthreads();
  sum = red[0] + red[1] + red[2] + red[3];
  sq  = red[4] + red[5] + red[6] + red[7];
  float mean = sum * (1.f / 1024.f);
  float var  = sq * (1.f / 1024.f) - mean * mean;
  float rs = rsqrtf(var + 1e-5f);
  float4 gv = *(const float4*)&gam[tid * 4];
  float4 bt = *(const float4*)&bet[tid * 4];
  float o0 = (s0 - mean) * rs * gv.x + bt.x;
  float o1 = (s1 - mean) * rs * gv.y + bt.y;
  float o2 = (s2 - mean) * rs * gv.z + bt.z;
  float o3 = (s3 - mean) * rs * gv.w + bt.w;
  float4 ov = { o0, o1, o2, o3 };
  *(float4*)&Of[base] = ov;
  if (WB){
    ushort4 ob = { f2bf(o0), f2bf(o1), f2bf(o2), f2bf(o3) };
    *(ushort4*)&Ob[base] = ob;
  }
}

// ---------------- orchestration ----------------
extern "C" void kernel_launch(void* const* d_in, const int* in_sizes, int n_in,
                              void* d_out, int out_size, void* d_ws, size_t ws_size,
                              hipStream_t stream)
{
  const float* x    = (const float*)d_in[0];
  const int*   mask = (const int*)  d_in[1];
  const float* Wq = (const float*)d_in[2];
  const float* bq = (const float*)d_in[3];
  const float* Wk = (const float*)d_in[4];
  const float* bk = (const float*)d_in[5];
  const float* Wv = (const float*)d_in[6];
  const float* bv = (const float*)d_in[7];
  const float* Wo = (const float*)d_in[8];
  const float* bo = (const float*)d_in[9];
  const float* W1 = (const float*)d_in[10];
  const float* b1 = (const float*)d_in[11];
  const float* W2 = (const float*)d_in[12];
  const float* b2 = (const float*)d_in[13];
  const float* g1 = (const float*)d_in[14];
  const float* be1= (const float*)d_in[15];
  const float* g2 = (const float*)d_in[16];
  const float* be2= (const float*)d_in[17];
  float* out = (float*)d_out;

  char* ws = (char*)d_ws;
  size_t off = 0;
  auto alloc = [&](size_t bytes)->void*{ void* p = ws + off; off += (bytes + 255) & ~(size_t)255; return p; };
  ush* xb     = (ush*)alloc((size_t)MTOT * 1024 * 2);
  ush* wqkvT  = (ush*)alloc((size_t)3072 * 1024 * 2);
  ush* woT    = (ush*)alloc((size_t)1024 * 1024 * 2);
  ush* w1T    = (ush*)alloc((size_t)4096 * 1024 * 2);
  ush* w2T    = (ush*)alloc((size_t)1024 * 4096 * 2);
  float* bqkv = (float*)alloc(3072 * 4);
  ush* qkv    = (ush*)alloc((size_t)MTOT * 3072 * 2);   // reused (with ctx) as ff1
  ush* ctx    = (ush*)alloc((size_t)MTOT * 1024 * 2);
  float* part = (float*)alloc((size_t)4 * MTOT * 1024 * 4);  // split-K partials (64MB)
  float* h    = (float*)alloc((size_t)MTOT * 1024 * 4);
  ush* hb     = (ush*)alloc((size_t)MTOT * 1024 * 2);
  ush* ff1    = qkv;   // 32 MB span (qkv 24MB + ctx 8MB), both dead by then

  // 1. converts / transposes
  cvt_kernel<<<dim3(4096), dim3(256), 0, stream>>>(x, xb, MTOT * 1024);
  tconv_kernel<<<dim3(32, 32), dim3(256), 0, stream>>>(Wq, wqkvT,               1024, 1024);
  tconv_kernel<<<dim3(32, 32), dim3(256), 0, stream>>>(Wk, wqkvT + 1024 * 1024, 1024, 1024);
  tconv_kernel<<<dim3(32, 32), dim3(256), 0, stream>>>(Wv, wqkvT + 2048 * 1024, 1024, 1024);
  tconv_kernel<<<dim3(32, 32), dim3(256), 0, stream>>>(Wo, woT,                 1024, 1024);
  tconv_kernel<<<dim3(128, 32), dim3(256), 0, stream>>>(W1, w1T, 1024, 4096);
  tconv_kernel<<<dim3(32, 128), dim3(256), 0, stream>>>(W2, w2T, 4096, 1024);
  biaspack_kernel<<<dim3(12), dim3(256), 0, stream>>>(bq, bk, bv, bqkv);

  // 2. QKV projection: [4096,3072] bf16
  gemm8_kernel<0, 0><<<dim3(12, 16, 1), dim3(512), 0, stream>>>(
      xb, wqkvT, bqkv, qkv, nullptr, MTOT, 3072, 1024, 3072, 1024);

  // 3. attention -> ctx bf16 [4096,1024]
  attn_kernel<<<dim3(16, 64), dim3(256), 0, stream>>>(qkv, mask, ctx);

  // 4. Wo partials: split-K=4, f32 [4][4096][1024]
  gemm8_kernel<0, 1><<<dim3(4, 16, 4), dim3(512), 0, stream>>>(
      ctx, woT, nullptr, nullptr, part, MTOT, 1024, 1024, 1024, 256);

  // 5. h = LN(x + sum(part) + bo)
  ln4_kernel<true><<<dim3(4096), dim3(256), 0, stream>>>(x, part, bo, g1, be1, h, hb);

  // 6. ff1 = relu(h @ W1 + b1) bf16 [4096,4096]
  gemm8_kernel<1, 0><<<dim3(16, 16, 1), dim3(512), 0, stream>>>(
      hb, w1T, b1, ff1, nullptr, MTOT, 4096, 1024, 4096, 1024);

  // 7. FF2 partials: split-K=4 over K=4096
  gemm8_kernel<0, 1><<<dim3(4, 16, 4), dim3(512), 0, stream>>>(
      ff1, w2T, nullptr, nullptr, part, MTOT, 1024, 4096, 1024, 1024);

  // 8. out = LN(h + sum(part) + b2)
  ln4_kernel<false><<<dim3(4096), dim3(256), 0, stream>>>(h, part, b2, g2, be2, out, nullptr);
}

// Round 3
// 390.358 us; speedup vs baseline: 1.1871x; 1.0672x over previous
//
#include <hip/hip_runtime.h>
#include <hip/hip_bf16.h>

typedef __attribute__((ext_vector_type(8))) short bf16x8;
typedef __attribute__((ext_vector_type(4))) float f32x4;
typedef __attribute__((ext_vector_type(16))) float f32x16;
typedef unsigned int u32;
typedef unsigned short ush;

#define SEQ 1024
#define MTOT 4096   // B*S
#define QSCALE_LOG2 0.18033688f   // log2(e)/8

#if __has_builtin(__builtin_amdgcn_exp2f)
#define EXP2(x) __builtin_amdgcn_exp2f(x)
#else
#define EXP2(x) exp2f(x)
#endif

__device__ __forceinline__ ush f2bf(float f){
  u32 u = __float_as_uint(f);
  u32 r = (u + 0x7fffu + ((u >> 16) & 1u)) >> 16;
  return (ush)r;
}

__device__ __forceinline__ f32x4 mfma16(bf16x8 a, bf16x8 b, f32x4 c){
  return __builtin_amdgcn_mfma_f32_16x16x32_bf16(a, b, c, 0, 0, 0);
}
__device__ __forceinline__ f32x16 mfma32(bf16x8 a, bf16x8 b, f32x16 c){
  return __builtin_amdgcn_mfma_f32_32x32x16_bf16(a, b, c, 0, 0, 0);
}

__device__ __forceinline__ u32 cvtpk(float lo, float hi){
  u32 r; asm("v_cvt_pk_bf16_f32 %0, %1, %2" : "=v"(r) : "v"(lo), "v"(hi)); return r;
}

__device__ __forceinline__ void gload_lds16(const ush* g, ush* l){
  __builtin_amdgcn_global_load_lds(
      (const __attribute__((address_space(1))) u32*)g,
      (__attribute__((address_space(3))) u32*)l, 16, 0, 0);
}

// ---------------- elementwise convert f32 -> bf16 ----------------
__global__ __launch_bounds__(256) void cvt_kernel(const float* __restrict__ src,
                                                  ush* __restrict__ dst, int n){
  int i = (blockIdx.x * 256 + threadIdx.x) * 4;
  if (i < n){
    float4 v = *(const float4*)&src[i];
    ushort4 o = { f2bf(v.x), f2bf(v.y), f2bf(v.z), f2bf(v.w) };
    *(ushort4*)&dst[i] = o;
  }
}

// ---------------- transpose + convert: dst[c][r] = bf16(src[r][c]) ----------------
__global__ __launch_bounds__(256) void tconv_kernel(const float* __restrict__ src,
                                                    ush* __restrict__ dst, int R, int C){
  __shared__ float t[32][33];
  int tx = threadIdx.x & 31, ty = threadIdx.x >> 5;
  int r0 = blockIdx.y * 32, c0 = blockIdx.x * 32;
  #pragma unroll
  for (int i = 0; i < 32; i += 8)
    t[ty + i][tx] = src[(size_t)(r0 + ty + i) * C + (c0 + tx)];
  __syncthreads();
  #pragma unroll
  for (int i = 0; i < 32; i += 8)
    dst[(size_t)(c0 + ty + i) * R + (r0 + tx)] = f2bf(t[tx][ty + i]);
}

__global__ __launch_bounds__(256) void biaspack_kernel(const float* __restrict__ bq,
    const float* __restrict__ bk, const float* __restrict__ bv, float* __restrict__ dst){
  int i = blockIdx.x * 256 + threadIdx.x;
  if (i < 3072){
    float v = (i < 1024) ? bq[i] : (i < 2048) ? bk[i - 1024] : bv[i - 2048];
    dst[i] = v;
  }
}

// ---------------- V transpose: VT[bh*64+d][key] = qkv[b*S+key][2048+h*64+d] ----------------
__global__ __launch_bounds__(256) void vtrans_kernel(const ush* __restrict__ qkv,
                                                     ush* __restrict__ VT){
  __shared__ ush t[32][34];
  int tx = threadIdx.x & 31, ty = threadIdx.x >> 5;   // ty 0..7
  int bh = blockIdx.z, b = bh >> 4, h = bh & 15;
  int k0 = blockIdx.x * 32, d0 = blockIdx.y * 32;
  #pragma unroll
  for (int i = 0; i < 32; i += 8)
    t[ty + i][tx] = qkv[(size_t)(b * SEQ + k0 + ty + i) * 3072 + 2048 + h * 64 + d0 + tx];
  __syncthreads();
  #pragma unroll
  for (int i = 0; i < 32; i += 8)
    VT[(size_t)(bh * 64 + d0 + ty + i) * SEQ + k0 + tx] = t[tx][ty + i];
}

// =====================================================================
// 256x256 8-phase GEMM (unchanged structure from round 2; +SCALEQ epilogue)
// =====================================================================
__device__ __forceinline__ void stage_piece(ush* piece, const ush* g0, int K,
                                            int tid, int w){
  #pragma unroll
  for (int I = 0; I < 2; I++){
    int c = I * 512 + tid;
    int r = c >> 2;
    int gl = (c & 3) ^ ((r >> 1) & 3);
    gload_lds16(g0 + (size_t)r * K + gl * 8, piece + I * 4096 + w * 512);
  }
}

__device__ __forceinline__ bf16x8 frag(const ush* piece, int row, int g){
  int phys = g ^ ((row >> 1) & 3);
  return *(const bf16x8*)(piece + row * 32 + phys * 8);
}

#define PH_BAR_TOP() do{ __builtin_amdgcn_sched_barrier(0); \
  __builtin_amdgcn_s_barrier(); \
  asm volatile("s_waitcnt lgkmcnt(0)" ::: "memory"); \
  __builtin_amdgcn_sched_barrier(0); \
  __builtin_amdgcn_s_setprio(1); }while(0)
#define PH_BAR_BOT() do{ __builtin_amdgcn_s_setprio(0); \
  __builtin_amdgcn_sched_barrier(0); \
  __builtin_amdgcn_s_barrier(); }while(0)

template<int RELU, int OUTF32, int SCALEQ>
__global__ __launch_bounds__(512, 2) void gemm8_kernel(
    const ush* __restrict__ A, const ush* __restrict__ Bt,
    const float* __restrict__ bias,
    ush* __restrict__ Cb, float* __restrict__ Cf,
    int M, int N, int K, int ldc, int ksl)
{
  __shared__ ush lds[2][2][2][8192];   // [buf][A/B][ks][16KB piece]
  const int tid = threadIdx.x;
  const int lane = tid & 63, w = tid >> 6;
  const int g = lane >> 4, qr = lane & 15;
  const int wr = w >> 2, wc = w & 3;
  const int gx = gridDim.x;
  const int nwg = gx * gridDim.y;
  const int id = blockIdx.y * gx + blockIdx.x;
  const int swz = (id & 7) * (nwg >> 3) + (id >> 3);
  const int bn = (swz % gx) * 256;
  const int bm = (swz / gx) * 256;
  const int kbase = blockIdx.z * ksl;
  const int NT = ksl >> 6;
  const ush* Ab = A  + (size_t)bm * K + kbase;
  const ush* Bb = Bt + (size_t)bn * K + kbase;

  stage_piece(lds[0][0][0], Ab,      K, tid, w);
  stage_piece(lds[0][1][0], Bb,      K, tid, w);
  stage_piece(lds[0][0][1], Ab + 32, K, tid, w);
  stage_piece(lds[0][1][1], Bb + 32, K, tid, w);
  if (NT > 1){
    stage_piece(lds[1][0][0], Ab + 64, K, tid, w);
    stage_piece(lds[1][1][0], Bb + 64, K, tid, w);
  }
  asm volatile("s_waitcnt vmcnt(4)" ::: "memory");
  __builtin_amdgcn_sched_barrier(0);
  __builtin_amdgcn_s_barrier();

  f32x4 acc[8][4] = {};
  const int ar = wr * 128 + qr;
  const int br = wc * 64 + qr;

  for (int T = 0; T < NT; ++T){
    const int cb = T & 1, nb = cb ^ 1;
    const ush* An = Ab + (size_t)(T + 1) * 64;
    const ush* Bn = Bb + (size_t)(T + 1) * 64;
    const ush* Af = Ab + (size_t)(T + 2) * 64;
    const ush* Bf = Bb + (size_t)(T + 2) * 64;
    bf16x8 af[4], bfr[4];

    #pragma unroll
    for (int j = 0; j < 4; j++) bfr[j] = frag(lds[cb][1][0], br + j * 16, g);
    #pragma unroll
    for (int i = 0; i < 4; i++) af[i] = frag(lds[cb][0][0], ar + i * 16, g);
    if (T + 1 < NT) stage_piece(lds[nb][0][1], An + 32, K, tid, w);
    PH_BAR_TOP();
    #pragma unroll
    for (int i = 0; i < 4; i++)
      #pragma unroll
      for (int j = 0; j < 4; j++)
        acc[i][j] = mfma16(af[i], bfr[j], acc[i][j]);
    PH_BAR_BOT();

    #pragma unroll
    for (int i = 0; i < 4; i++) af[i] = frag(lds[cb][0][0], ar + 64 + i * 16, g);
    if (T + 1 < NT) stage_piece(lds[nb][1][1], Bn + 32, K, tid, w);
    PH_BAR_TOP();
    #pragma unroll
    for (int i = 0; i < 4; i++)
      #pragma unroll
      for (int j = 0; j < 4; j++)
        acc[4 + i][j] = mfma16(af[i], bfr[j], acc[4 + i][j]);
    PH_BAR_BOT();

    #pragma unroll
    for (int j = 0; j < 4; j++) bfr[j] = frag(lds[cb][1][1], br + j * 16, g);
    #pragma unroll
    for (int i = 0; i < 4; i++) af[i] = frag(lds[cb][0][1], ar + i * 16, g);
    if (T + 2 < NT) stage_piece(lds[cb][0][0], Af, K, tid, w);
    PH_BAR_TOP();
    #pragma unroll
    for (int i = 0; i < 4; i++)
      #pragma unroll
      for (int j = 0; j < 4; j++)
        acc[i][j] = mfma16(af[i], bfr[j], acc[i][j]);
    PH_BAR_BOT();

    #pragma unroll
    for (int i = 0; i < 4; i++) af[i] = frag(lds[cb][0][1], ar + 64 + i * 16, g);
    if (T + 2 < NT) stage_piece(lds[cb][1][0], Bf, K, tid, w);
    PH_BAR_TOP();
    #pragma unroll
    for (int i = 0; i < 4; i++)
      #pragma unroll
      for (int j = 0; j < 4; j++)
        acc[4 + i][j] = mfma16(af[i], bfr[j], acc[4 + i][j]);
    __builtin_amdgcn_s_setprio(0);
    __builtin_amdgcn_sched_barrier(0);
    asm volatile("s_waitcnt vmcnt(4)" ::: "memory");
    __builtin_amdgcn_sched_barrier(0);
    __builtin_amdgcn_s_barrier();
  }

  float* Cfz = Cf;
  if (OUTF32) Cfz = Cf + (size_t)blockIdx.z * M * ldc;
  #pragma unroll
  for (int j = 0; j < 4; j++){
    const int col = bn + wc * 64 + j * 16 + qr;
    const float bv = OUTF32 ? 0.f : bias[col];
    const float scl = (SCALEQ && col < 1024) ? QSCALE_LOG2 : 1.f;
    #pragma unroll
    for (int i = 0; i < 8; i++){
      const int row0 = bm + wr * 128 + i * 16 + g * 4;
      #pragma unroll
      for (int rr = 0; rr < 4; rr++){
        float v = acc[i][j][rr] + bv;
        if (RELU) v = fmaxf(v, 0.f);
        if (SCALEQ) v *= scl;
        const size_t idx = (size_t)(row0 + rr) * ldc + col;
        if (OUTF32) Cfz[idx] = v; else Cb[idx] = f2bf(v);
      }
    }
  }
}

// =====================================================================
// Flash attention v2: LDS-free, 32x32x16 MFMA, swapped QK^T,
// in-register softmax (cvt_pk + permlane32_swap), exp2 domain.
// Q is pre-scaled by log2(e)/8 in the QKV GEMM epilogue.
// grid: (S/128, B*H), block 256 (4 warps x 32 q-rows each).
// =====================================================================
__global__ __launch_bounds__(256) void attn2_kernel(
    const ush* __restrict__ qkv, const ush* __restrict__ VT,
    const int* __restrict__ mask, ush* __restrict__ ctx)
{
  const int tid = threadIdx.x;
  const int lane = tid & 63, w = tid >> 6;
  const int c = lane & 31, hi = lane >> 5;
  const int bh = blockIdx.y, b = bh >> 4, hh = bh & 15;
  const int q0 = blockIdx.x * 128 + w * 32;

  // block-uniform "mask is all ones" fast-path check
  __shared__ int mflag;
  if (tid == 0) mflag = 1;
  __syncthreads();
  {
    int4 mv = *(const int4*)&mask[b * SEQ + tid * 4];
    if (!(mv.x && mv.y && mv.z && mv.w)) mflag = 0;
  }
  __syncthreads();
  const bool maskall = (mflag != 0);

  // Q fragments (B-operand of swapped QK^T): lane holds Q[q0+c][kd*16+hi*8 + j]
  const ush* Qrow = qkv + (size_t)(b * SEQ + q0 + c) * 3072 + hh * 64;
  bf16x8 qf[4];
  #pragma unroll
  for (int kd = 0; kd < 4; kd++)
    qf[kd] = *(const bf16x8*)(Qrow + kd * 16 + hi * 8);

  const ush* Kb  = qkv + (size_t)(b * SEQ) * 3072 + 1024 + hh * 64;  // K rows, stride 3072
  const ush* VTb = VT + (size_t)(bh * 64) * SEQ;                     // V^T rows d, stride SEQ

  f32x16 o0 = {}, o1 = {};
  float m_run = -1e30f, l_run = 0.f;

  // prologue: K fragments for tile 0: kf[kb*4+kd] = K[kb*32+c][kd*16+hi*8+j]
  bf16x8 kf[8];
  #pragma unroll
  for (int kb = 0; kb < 2; kb++)
    #pragma unroll
    for (int kd = 0; kd < 4; kd++)
      kf[kb * 4 + kd] = *(const bf16x8*)(Kb + (size_t)(kb * 32 + c) * 3072 + kd * 16 + hi * 8);

  for (int t = 0; t < SEQ / 64; ++t){
    const int k0 = t * 64;
    // issue V B-frags early: vf[db*4+ks] = V^T[db*32+c][k0+ks*16+hi*8 + j]
    bf16x8 vf[8];
    #pragma unroll
    for (int db = 0; db < 2; db++)
      #pragma unroll
      for (int ks = 0; ks < 4; ks++)
        vf[db * 4 + ks] = *(const bf16x8*)(VTb + (size_t)(db * 32 + c) * SEQ + k0 + ks * 16 + hi * 8);

    // QK^T (swapped): S^T[key][q], two 32-key accumulators
    f32x16 s0 = {}, s1 = {};
    #pragma unroll
    for (int kd = 0; kd < 4; kd++){
      s0 = mfma32(kf[kd],     qf[kd], s0);
      s1 = mfma32(kf[4 + kd], qf[kd], s1);
    }

    // p[r32] = S[q=c][key = (r32>>4)*32 + crow(r32&15, hi)]
    float p[32];
    #pragma unroll
    for (int r = 0; r < 16; r++){ p[r] = s0[r]; p[16 + r] = s1[r]; }

    if (!maskall){
      #pragma unroll
      for (int r32 = 0; r32 < 32; r32++){
        int r = r32 & 15;
        int key = (r32 >> 4) * 32 + (r & 3) + 8 * (r >> 2) + 4 * hi;
        if (mask[b * SEQ + k0 + key] == 0) p[r32] = -1e9f;
      }
    }

    // prefetch K frags for next tile (lands under softmax)
    if (t + 1 < SEQ / 64){
      #pragma unroll
      for (int kb = 0; kb < 2; kb++)
        #pragma unroll
        for (int kd = 0; kd < 4; kd++)
          kf[kb * 4 + kd] = *(const bf16x8*)(Kb + (size_t)(k0 + 64 + kb * 32 + c) * 3072 + kd * 16 + hi * 8);
    }

    // online softmax (log2 domain), defer-max THR=8
    float pmax = p[0];
    #pragma unroll
    for (int r = 1; r < 32; r++) pmax = fmaxf(pmax, p[r]);
    pmax = fmaxf(pmax, __shfl_xor(pmax, 32));
    if (__any(pmax > m_run + 8.f)){
      float m_new = fmaxf(m_run, pmax);
      float corr = EXP2(m_run - m_new);
      l_run *= corr;
      m_run = m_new;
      #pragma unroll
      for (int r = 0; r < 16; r++){
        float cr = __shfl(corr, (r & 3) + 8 * (r >> 2) + 4 * hi);
        o0[r] *= cr; o1[r] *= cr;
      }
    }
    float ls = 0.f;
    #pragma unroll
    for (int r = 0; r < 32; r++){ p[r] = EXP2(p[r] - m_run); ls += p[r]; }
    ls += __shfl_xor(ls, 32);
    l_run += ls;

    // P -> bf16 A-frags: 16 cvt_pk + 8 permlane32_swap
    union { u32 wdw[4]; bf16x8 v; } af[4];
    #pragma unroll
    for (int ks = 0; ks < 4; ks++){
      int b0 = (ks >> 1) * 16 + 8 * (ks & 1);
      u32 c00 = cvtpk(p[b0],     p[b0 + 1]);
      u32 c01 = cvtpk(p[b0 + 2], p[b0 + 3]);
      u32 c10 = cvtpk(p[b0 + 4], p[b0 + 5]);
      u32 c11 = cvtpk(p[b0 + 6], p[b0 + 7]);
      asm volatile("v_permlane32_swap_b32 %0, %1" : "+v"(c10), "+v"(c00));
      asm volatile("v_permlane32_swap_b32 %0, %1" : "+v"(c11), "+v"(c01));
      af[ks].wdw[0] = c00; af[ks].wdw[1] = c01; af[ks].wdw[2] = c10; af[ks].wdw[3] = c11;
    }

    // PV: O[q][d] += P V
    #pragma unroll
    for (int ks = 0; ks < 4; ks++){
      o0 = mfma32(af[ks].v, vf[ks],     o0);
      o1 = mfma32(af[ks].v, vf[4 + ks], o1);
    }
  }

  float linv = 1.f / l_run;
  #pragma unroll
  for (int r = 0; r < 16; r++){
    int crow = (r & 3) + 8 * (r >> 2) + 4 * hi;
    float li = __shfl(linv, crow);
    size_t base = (size_t)(b * SEQ + q0 + crow) * 1024 + hh * 64;
    ctx[base + c]      = f2bf(o0[r] * li);
    ctx[base + 32 + c] = f2bf(o1[r] * li);
  }
}

// -------- residual + 4-way split-K reduce + bias + LayerNorm --------
template<bool WB>
__global__ __launch_bounds__(256) void ln4_kernel(
    const float* __restrict__ X, const float* __restrict__ P,
    const float* __restrict__ bias,
    const float* __restrict__ gam, const float* __restrict__ bet,
    float* __restrict__ Of, ush* __restrict__ Ob)
{
  const int row = blockIdx.x, tid = threadIdx.x;
  const size_t base = (size_t)row * 1024 + tid * 4;
  float4 xv = *(const float4*)&X[base];
  float4 bv4 = *(const float4*)&bias[tid * 4];
  float s0 = xv.x + bv4.x, s1 = xv.y + bv4.y, s2 = xv.z + bv4.z, s3 = xv.w + bv4.w;
  #pragma unroll
  for (int z = 0; z < 4; z++){
    float4 p = *(const float4*)&P[(size_t)z * 4194304 + base];
    s0 += p.x; s1 += p.y; s2 += p.z; s3 += p.w;
  }
  float sum = s0 + s1 + s2 + s3;
  float sq  = s0 * s0 + s1 * s1 + s2 * s2 + s3 * s3;
  #pragma unroll
  for (int o = 1; o < 64; o <<= 1){ sum += __shfl_xor(sum, o); sq += __shfl_xor(sq, o); }
  __shared__ float red[8];
  int lane = tid & 63, w = tid >> 6;
  if (lane == 0){ red[w] = sum; red[4 + w] = sq; }
  __syncthreads();
  sum = red[0] + red[1] + red[2] + red[3];
  sq  = red[4] + red[5] + red[6] + red[7];
  float mean = sum * (1.f / 1024.f);
  float var  = sq * (1.f / 1024.f) - mean * mean;
  float rs = rsqrtf(var + 1e-5f);
  float4 gv = *(const float4*)&gam[tid * 4];
  float4 bt = *(const float4*)&bet[tid * 4];
  float o0 = (s0 - mean) * rs * gv.x + bt.x;
  float o1 = (s1 - mean) * rs * gv.y + bt.y;
  float o2 = (s2 - mean) * rs * gv.z + bt.z;
  float o3 = (s3 - mean) * rs * gv.w + bt.w;
  float4 ov = { o0, o1, o2, o3 };
  *(float4*)&Of[base] = ov;
  if (WB){
    ushort4 ob = { f2bf(o0), f2bf(o1), f2bf(o2), f2bf(o3) };
    *(ushort4*)&Ob[base] = ob;
  }
}

// ---------------- orchestration ----------------
extern "C" void kernel_launch(void* const* d_in, const int* in_sizes, int n_in,
                              void* d_out, int out_size, void* d_ws, size_t ws_size,
                              hipStream_t stream)
{
  const float* x    = (const float*)d_in[0];
  const int*   mask = (const int*)  d_in[1];
  const float* Wq = (const float*)d_in[2];
  const float* bq = (const float*)d_in[3];
  const float* Wk = (const float*)d_in[4];
  const float* bk = (const float*)d_in[5];
  const float* Wv = (const float*)d_in[6];
  const float* bv = (const float*)d_in[7];
  const float* Wo = (const float*)d_in[8];
  const float* bo = (const float*)d_in[9];
  const float* W1 = (const float*)d_in[10];
  const float* b1 = (const float*)d_in[11];
  const float* W2 = (const float*)d_in[12];
  const float* b2 = (const float*)d_in[13];
  const float* g1 = (const float*)d_in[14];
  const float* be1= (const float*)d_in[15];
  const float* g2 = (const float*)d_in[16];
  const float* be2= (const float*)d_in[17];
  float* out = (float*)d_out;

  char* ws = (char*)d_ws;
  size_t off = 0;
  auto alloc = [&](size_t bytes)->void*{ void* p = ws + off; off += (bytes + 255) & ~(size_t)255; return p; };
  ush* xb     = (ush*)alloc((size_t)MTOT * 1024 * 2);
  ush* wqkvT  = (ush*)alloc((size_t)3072 * 1024 * 2);
  ush* woT    = (ush*)alloc((size_t)1024 * 1024 * 2);
  ush* w1T    = (ush*)alloc((size_t)4096 * 1024 * 2);
  ush* w2T    = (ush*)alloc((size_t)1024 * 4096 * 2);
  float* bqkv = (float*)alloc(3072 * 4);
  ush* qkv    = (ush*)alloc((size_t)MTOT * 3072 * 2);   // reused (with ctx) as ff1
  ush* ctx    = (ush*)alloc((size_t)MTOT * 1024 * 2);
  float* part = (float*)alloc((size_t)4 * MTOT * 1024 * 4);  // split-K partials
  float* h    = (float*)alloc((size_t)MTOT * 1024 * 4);
  ush* hb     = (ush*)alloc((size_t)MTOT * 1024 * 2);
  ush* VT     = (ush*)alloc((size_t)64 * 64 * SEQ * 2);      // V^T per (b,h): [64 d][1024 keys]
  ush* ff1    = qkv;   // 32 MB span (qkv 24MB + ctx 8MB), both dead by then

  // 1. converts / transposes
  cvt_kernel<<<dim3(4096), dim3(256), 0, stream>>>(x, xb, MTOT * 1024);
  tconv_kernel<<<dim3(32, 32), dim3(256), 0, stream>>>(Wq, wqkvT,               1024, 1024);
  tconv_kernel<<<dim3(32, 32), dim3(256), 0, stream>>>(Wk, wqkvT + 1024 * 1024, 1024, 1024);
  tconv_kernel<<<dim3(32, 32), dim3(256), 0, stream>>>(Wv, wqkvT + 2048 * 1024, 1024, 1024);
  tconv_kernel<<<dim3(32, 32), dim3(256), 0, stream>>>(Wo, woT,                 1024, 1024);
  tconv_kernel<<<dim3(128, 32), dim3(256), 0, stream>>>(W1, w1T, 1024, 4096);
  tconv_kernel<<<dim3(32, 128), dim3(256), 0, stream>>>(W2, w2T, 4096, 1024);
  biaspack_kernel<<<dim3(12), dim3(256), 0, stream>>>(bq, bk, bv, bqkv);

  // 2. QKV projection (Q pre-scaled by log2e/8 in epilogue)
  gemm8_kernel<0, 0, 1><<<dim3(12, 16, 1), dim3(512), 0, stream>>>(
      xb, wqkvT, bqkv, qkv, nullptr, MTOT, 3072, 1024, 3072, 1024);

  // 3. V transpose for attention B-frags
  vtrans_kernel<<<dim3(32, 2, 64), dim3(256), 0, stream>>>(qkv, VT);

  // 4. attention -> ctx bf16 [4096,1024]
  attn2_kernel<<<dim3(8, 64), dim3(256), 0, stream>>>(qkv, VT, mask, ctx);

  // 5. Wo partials: split-K=4, f32 [4][4096][1024]
  gemm8_kernel<0, 1, 0><<<dim3(4, 16, 4), dim3(512), 0, stream>>>(
      ctx, woT, nullptr, nullptr, part, MTOT, 1024, 1024, 1024, 256);

  // 6. h = LN(x + sum(part) + bo)
  ln4_kernel<true><<<dim3(4096), dim3(256), 0, stream>>>(x, part, bo, g1, be1, h, hb);

  // 7. ff1 = relu(h @ W1 + b1) bf16 [4096,4096]
  gemm8_kernel<1, 0, 0><<<dim3(16, 16, 1), dim3(512), 0, stream>>>(
      hb, w1T, b1, ff1, nullptr, MTOT, 4096, 1024, 4096, 1024);

  // 8. FF2 partials: split-K=4 over K=4096
  gemm8_kernel<0, 1, 0><<<dim3(4, 16, 4), dim3(512), 0, stream>>>(
      ff1, w2T, nullptr, nullptr, part, MTOT, 1024, 4096, 1024, 1024);

  // 9. out = LN(h + sum(part) + b2)
  ln4_kernel<false><<<dim3(4096), dim3(256), 0, stream>>>(h, part, b2, g2, be2, out, nullptr);
}